// Round 26
// baseline (112.291 us; speedup 1.0000x reference)
//
#include <hip/hip_runtime.h>
#include <math.h>

constexpr int NQ      = 14;
constexpr int NSTATE  = 1 << 14;    // 16384
constexpr int NPARAMS = 140;
constexpr int BATCH   = 128;
constexpr int THREADS = 1024;
constexpr int REGS    = 16;         // amp index = r*1024 + tid (bits 13..10 = r)

struct cplx { float re, im; };
__device__ __forceinline__ cplx cmul(cplx a, cplx b) {
    return { a.re*b.re - a.im*b.im, a.re*b.im + a.im*b.re };
}
__device__ __forceinline__ float2 axpb(cplx A, float2 own, cplx B, float2 par) {
    return make_float2(A.re*own.x - A.im*own.y + B.re*par.x - B.im*par.y,
                       A.re*own.y + A.im*own.x + B.re*par.y + B.im*par.x);
}
__device__ __forceinline__ unsigned int f2bf(float f) {
    union { float f; unsigned int u; } v; v.f = f;
    return (v.u + 0x7FFFu + ((v.u >> 16) & 1u)) >> 16;
}
__device__ __forceinline__ constexpr int ins1(int j, int rb) {
    int lo = j & ((1 << rb) - 1);
    return ((j ^ lo) << 1) | (1 << rb) | lo;
}
__device__ __forceinline__ void gate_fence() {
    __builtin_amdgcn_sched_barrier(0);
}

// xor-shuffle across lanes. Masks 1,2,4,8 on the VALU pipe (DPP), 16/32 on LDS pipe.
// quad_perm[1,0,3,2]=0xB1 (xor1), [2,3,0,1]=0x4E (xor2), [3,2,1,0]=0x1B (xor3)
// ROW_MIRROR=0x140 (xor15), ROW_HALF_MIRROR=0x141 (xor7); xor4=xor7*xor3, xor8=xor15*xor7
template<int MASK>
__device__ __forceinline__ float lane_xor(float v) {
    if constexpr (MASK >= 16) {
        return __shfl_xor(v, MASK, 64);
    } else {
        int x = __float_as_int(v);
        if constexpr (MASK == 1) {
            x = __builtin_amdgcn_update_dpp(x, x, 0xB1, 0xF, 0xF, true);
        } else if constexpr (MASK == 2) {
            x = __builtin_amdgcn_update_dpp(x, x, 0x4E, 0xF, 0xF, true);
        } else if constexpr (MASK == 4) {
            x = __builtin_amdgcn_update_dpp(x, x, 0x141, 0xF, 0xF, true);
            x = __builtin_amdgcn_update_dpp(x, x, 0x1B, 0xF, 0xF, true);
        } else {  // 8
            x = __builtin_amdgcn_update_dpp(x, x, 0x140, 0xF, 0xF, true);
            x = __builtin_amdgcn_update_dpp(x, x, 0x141, 0xF, 0xF, true);
        }
        return __int_as_float(x);
    }
}

// ---------- 1q gate, register bit RB (amp bit 10+RB) ----------
template<int RB>
__device__ __forceinline__ void u1_local(float2 (&a)[REGS],
                                         cplx u00, cplx u01, cplx u10, cplx u11) {
    #pragma unroll
    for (int r = 0; r < REGS; ++r) {
        if (r & (1 << RB)) continue;
        const int r1 = r | (1 << RB);
        float2 n0 = axpb(u00, a[r],  u01, a[r1]);
        float2 n1 = axpb(u11, a[r1], u10, a[r]);
        a[r] = n0; a[r1] = n1;
    }
}

// ---------- 1q gate, lane bit (MASK = 1..32) ----------
template<int MASK>
__device__ __forceinline__ void u1_lane(float2 (&a)[REGS], int tid,
                                        cplx u00, cplx u01, cplx u10, cplx u11) {
    const bool hi = (tid & MASK) != 0;
    const cplx A = hi ? u11 : u00;
    const cplx B = hi ? u10 : u01;
    #pragma unroll
    for (int r = 0; r < REGS; ++r) {
        float px = lane_xor<MASK>(a[r].x);
        float py = lane_xor<MASK>(a[r].y);
        a[r] = axpb(A, a[r], B, make_float2(px, py));
    }
}

// ---------- 1q gate, wave bit TMASK (64,128,256,512 in tid space) ----------
template<int TMASK>
__device__ __forceinline__ void u1_wave(float2 (&a)[REGS], int tid,
                                        cplx u00, cplx u01, cplx u10, cplx u11,
                                        float4* xch) {
    const bool hi = (tid & TMASK) != 0;
    const cplx A = hi ? u11 : u00;
    const cplx B = hi ? u10 : u01;
    __syncthreads();
    #pragma unroll
    for (int j = 0; j < 8; ++j)
        xch[j*1024 + tid] = make_float4(a[2*j].x, a[2*j].y, a[2*j+1].x, a[2*j+1].y);
    __syncthreads();
    const int pr = tid ^ TMASK;
    #pragma unroll
    for (int j = 0; j < 8; ++j) {
        float4 p = xch[j*1024 + pr];
        a[2*j]   = axpb(A, a[2*j],   B, make_float2(p.x, p.y));
        a[2*j+1] = axpb(A, a[2*j+1], B, make_float2(p.z, p.w));
    }
}

// ---------- CRX, target reg bit RB, control bit PC ----------
template<int RB, int PC>
__device__ __forceinline__ void crx_local(float2 (&a)[REGS], int tid,
                                          float cr, float sr) {
    #pragma unroll
    for (int r = 0; r < REGS; ++r) {
        if (r & (1 << RB)) continue;
        const int r1 = r | (1 << RB);
        bool act;
        if constexpr (PC >= 10) act = ((r >> (PC - 10)) & 1) != 0;   // compile-time
        else                    act = ((tid >> PC) & 1) != 0;
        if (act) {
            float2 a0 = a[r], a1 = a[r1];
            a[r]  = make_float2(cr*a0.x + sr*a1.y, cr*a0.y - sr*a1.x);
            a[r1] = make_float2(cr*a1.x + sr*a0.y, cr*a1.y - sr*a0.x);
        }
    }
}

// ---------- CRX, target lane bit MASK, control bit PC ----------
template<int MASK, int PC>
__device__ __forceinline__ void crx_lane(float2 (&a)[REGS], int tid,
                                         float cr, float sr) {
    if constexpr (PC >= 10) {
        #pragma unroll
        for (int r = 0; r < REGS; ++r) {
            if (((r >> (PC - 10)) & 1) == 0) continue;   // inactive reg: no shuffle
            float px = lane_xor<MASK>(a[r].x);
            float py = lane_xor<MASK>(a[r].y);
            a[r] = make_float2(cr*a[r].x + sr*py, cr*a[r].y - sr*px);
        }
    } else {
        const bool act = ((tid >> PC) & 1) != 0;
        #pragma unroll
        for (int r = 0; r < REGS; ++r) {
            float px = lane_xor<MASK>(a[r].x);
            float py = lane_xor<MASK>(a[r].y);
            if (act) a[r] = make_float2(cr*a[r].x + sr*py, cr*a[r].y - sr*px);
        }
    }
}

// ---------- CRX, target wave bit TMASK, control bit PC ----------
template<int TMASK, int PC>
__device__ __forceinline__ void crx_wave(float2 (&a)[REGS], int tid,
                                         float cr, float sr, float4* xch) {
    if constexpr (PC >= 10) {
        constexpr int RB = PC - 10;                      // 8 active regs
        __syncthreads();
        #pragma unroll
        for (int j2 = 0; j2 < 4; ++j2) {
            constexpr int ra0[4] = { ins1(0,RB), ins1(2,RB), ins1(4,RB), ins1(6,RB) };
            constexpr int rb0[4] = { ins1(1,RB), ins1(3,RB), ins1(5,RB), ins1(7,RB) };
            xch[j2*1024 + tid] = make_float4(a[ra0[j2]].x, a[ra0[j2]].y,
                                             a[rb0[j2]].x, a[rb0[j2]].y);
        }
        __syncthreads();
        const int pr = tid ^ TMASK;
        #pragma unroll
        for (int j2 = 0; j2 < 4; ++j2) {
            constexpr int ra0[4] = { ins1(0,RB), ins1(2,RB), ins1(4,RB), ins1(6,RB) };
            constexpr int rb0[4] = { ins1(1,RB), ins1(3,RB), ins1(5,RB), ins1(7,RB) };
            float4 p = xch[j2*1024 + pr];
            const int ra = ra0[j2], rb = rb0[j2];
            a[ra] = make_float2(cr*a[ra].x + sr*p.y, cr*a[ra].y - sr*p.x);
            a[rb] = make_float2(cr*a[rb].x + sr*p.w, cr*a[rb].y - sr*p.z);
        }
    } else {
        const bool act = ((tid >> PC) & 1) != 0;
        __syncthreads();
        if (act) {
            #pragma unroll
            for (int j = 0; j < 8; ++j)
                xch[j*1024 + tid] = make_float4(a[2*j].x, a[2*j].y, a[2*j+1].x, a[2*j+1].y);
        }
        __syncthreads();
        if (act) {
            const int pr = tid ^ TMASK;
            #pragma unroll
            for (int j = 0; j < 8; ++j) {
                float4 p = xch[j*1024 + pr];
                a[2*j]   = make_float2(cr*a[2*j].x   + sr*p.y, cr*a[2*j].y   - sr*p.x);
                a[2*j+1] = make_float2(cr*a[2*j+1].x + sr*p.w, cr*a[2*j+1].y - sr*p.z);
            }
        }
    }
}

// ---------- compile-time dispatchers (P = amp-bit of target) ----------
template<int P>
__device__ __forceinline__ void fused1q_t(float2 (&a)[REGS], int tid, int idx,
                                          const float2* gcs, float4* xch) {
    const float2 x = gcs[idx], y = gcs[idx + 1], z = gcs[idx + 2];
    const float cx = x.x, sx = x.y, cy = y.x, sy = y.y, cz = z.x, sz = z.y;
    cplx m00{ cy*cx,  sy*sx }, m01{ -sy*cx, -cy*sx };
    cplx m10{ sy*cx, -cy*sx }, m11{  cy*cx, -sy*sx };
    cplx z0{ cz, -sz }, z1{ cz, sz };
    cplx u00 = cmul(z0, m00), u01 = cmul(z0, m01);
    cplx u10 = cmul(z1, m10), u11 = cmul(z1, m11);
    if constexpr (P >= 10)     u1_local<(P >= 10 ? P - 10 : 0)>(a, u00, u01, u10, u11);
    else if constexpr (P >= 6) u1_wave<(P >= 6 && P < 10 ? (1 << P) : 64)>(a, tid, u00, u01, u10, u11, xch);
    else                       u1_lane<(P < 6 ? (1 << P) : 1)>(a, tid, u00, u01, u10, u11);
}

template<int PC, int PT>
__device__ __forceinline__ void crx_t(float2 (&a)[REGS], int tid, int idx,
                                      const float2* gcs, float4* xch) {
    const float2 g = gcs[idx];
    const float cr = g.x, sr = g.y;
    if constexpr (PT >= 10)     crx_local<(PT >= 10 ? PT - 10 : 0), PC>(a, tid, cr, sr);
    else if constexpr (PT >= 6) crx_wave<(PT >= 6 && PT < 10 ? (1 << PT) : 64), PC>(a, tid, cr, sr, xch);
    else                        crx_lane<(PT < 6 ? (1 << PT) : 1), PC>(a, tid, cr, sr);
}

template<int I>
struct GateSeq {
    __device__ __forceinline__ static void run1q(float2 (&a)[REGS], int tid, int base,
                                                 const float2* gcs, float4* xch) {
        fused1q_t<NQ - 1 - I>(a, tid, base + 3 * I, gcs, xch);
        gate_fence();
        GateSeq<I + 1>::run1q(a, tid, base, gcs, xch);
    }
    __device__ __forceinline__ static void runAsc(float2 (&a)[REGS], int tid, int base,
                                                  const float2* gcs, float4* xch) {
        crx_t<NQ - 1 - I, NQ - 1 - ((I + 1) % NQ)>(a, tid, base + I, gcs, xch);
        gate_fence();
        GateSeq<I + 1>::runAsc(a, tid, base, gcs, xch);
    }
    __device__ __forceinline__ static void runDesc(float2 (&a)[REGS], int tid, int base,
                                                   const float2* gcs, float4* xch) {
        constexpr int i = NQ - 1 - I;                    // i = 13..0
        crx_t<NQ - 1 - i, NQ - 1 - ((i + 13) % NQ)>(a, tid, base + I, gcs, xch);
        gate_fence();
        GateSeq<I + 1>::runDesc(a, tid, base, gcs, xch);
    }
};
template<>
struct GateSeq<NQ> {
    __device__ __forceinline__ static void run1q (float2 (&)[REGS], int, int, const float2*, float4*) {}
    __device__ __forceinline__ static void runAsc(float2 (&)[REGS], int, int, const float2*, float4*) {}
    __device__ __forceinline__ static void runDesc(float2 (&)[REGS], int, int, const float2*, float4*) {}
};

__global__ __launch_bounds__(THREADS)
void qsim_kernel(const float* __restrict__ params,
                 unsigned int* __restrict__ out_u32) {
    __shared__ float4 xch[8192];       // 128 KiB exchange, column-major [8][1024]
    __shared__ float2 gcs[NPARAMS];    // (cos, sin) of half-angles

    const int b   = blockIdx.x;
    const int tid = threadIdx.x;

    if (tid < NPARAMS) {
        float s, c;
        sincosf(0.5f * params[b * NPARAMS + tid], &s, &c);
        gcs[tid] = make_float2(c, s);
    }

    float2 a[REGS];
    #pragma unroll
    for (int r = 0; r < REGS; ++r) a[r] = make_float2(0.f, 0.f);
    if (tid == 0) a[0] = make_float2(1.f, 0.f);   // amp 0 = r0, tid0
    __syncthreads();

    // layer 0
    GateSeq<0>::run1q (a, tid, 0,   gcs, xch);
    GateSeq<0>::runAsc(a, tid, 42,  gcs, xch);
    GateSeq<0>::runDesc(a, tid, 56, gcs, xch);
    // layer 1
    GateSeq<0>::run1q (a, tid, 70,  gcs, xch);
    GateSeq<0>::runAsc(a, tid, 112, gcs, xch);
    GateSeq<0>::runDesc(a, tid, 126, gcs, xch);

    // ---- epilogue: amp r*1024+tid -> word (im | re<<16); fully coalesced ----
    unsigned int* ob = out_u32 + (size_t)b * NSTATE + tid;
    #pragma unroll
    for (int r = 0; r < REGS; ++r)
        ob[r * 1024] = f2bf(a[r].y) | (f2bf(a[r].x) << 16);
}

extern "C" void kernel_launch(void* const* d_in, const int* in_sizes, int n_in,
                              void* d_out, int out_size, void* d_ws, size_t ws_size,
                              hipStream_t stream) {
    const float* params = (const float*)d_in[0];
    unsigned int* out = (unsigned int*)d_out;
    qsim_kernel<<<BATCH, THREADS, 0, stream>>>(params, out);
}

// Round 27
// 105.236 us; speedup vs baseline: 1.0670x; 1.0670x over previous
//
#include <hip/hip_runtime.h>
#include <math.h>

constexpr int NQ      = 14;
constexpr int NSTATE  = 1 << 14;    // 16384
constexpr int NPARAMS = 140;
constexpr int BATCH   = 128;
constexpr int THREADS = 1024;

struct cplx { float re, im; };
__device__ __forceinline__ cplx cmul(cplx a, cplx b) {
    return { a.re*b.re - a.im*b.im, a.re*b.im + a.im*b.re };
}
__device__ __forceinline__ unsigned int f2bf(float f) {
    union { float f; unsigned int u; } v; v.f = f;
    return (v.u + 0x7FFFu + ((v.u >> 16) & 1u)) >> 16;
}
// global LDS index swizzle: XOR bits 1-4 with bits 5-8 (bijective involution).
__device__ __forceinline__ int SWZ(int i) { return i ^ (((i >> 5) & 0xF) << 1); }

// Pass descriptor. type 0 = ONEQ (n fused-1q gates on n qubits),
//                  type 1 = CHAIN (n sequential CRX gates over n+1 qubits).
// bits[j] = global bit position of local qubit j (local MSB first).
struct Pass { unsigned char type, n, pb; unsigned char bits[4]; };
__device__ const Pass g_passes[14] = {
    {0,4,0,  {13,12,11,10}},   // 1q q0-q3
    {0,4,12, {9,8,7,6}},       // 1q q4-q7
    {0,4,24, {5,4,3,2}},       // 1q q8-q11
    {0,2,36, {1,0,0,0}},       // 1q q12,q13
    {1,3,42, {13,12,11,10}},   // asc CRX (0,1),(1,2),(2,3)
    {1,3,45, {10,9,8,7}},      // asc (3,4),(4,5),(5,6)
    {1,3,48, {7,6,5,4}},       // asc (6,7),(7,8),(8,9)
    {1,3,51, {4,3,2,1}},       // asc (9,10),(10,11),(11,12)
    {1,2,54, {1,0,13,0}},      // asc (12,13),(13,0)
    {1,3,56, {0,1,2,3}},       // desc (13,12),(12,11),(11,10)
    {1,3,59, {3,4,5,6}},       // desc (10,9),(9,8),(8,7)
    {1,3,62, {6,7,8,9}},       // desc (7,6),(6,5),(5,4)
    {1,3,65, {9,10,11,12}},    // desc (4,3),(3,2),(2,1)
    {1,2,68, {12,13,0,0}},     // desc (1,0),(0,13)
};

template<int NB>
__device__ __forceinline__ void sortbits(int (&s)[NB]) {
    #pragma unroll
    for (int i = 1; i < NB; ++i)
        #pragma unroll
        for (int j = 0; j < NB - 1; ++j)
            if (s[j] > s[j+1]) { int t = s[j]; s[j] = s[j+1]; s[j+1] = t; }
}
// insert zero-bits at positions s[] (ascending) into compressed index g
template<int NB>
__device__ __forceinline__ int expand(int g, const int (&s)[NB]) {
    int x = g;
    #pragma unroll
    for (int j = 0; j < NB; ++j) {
        int m = (1 << s[j]) - 1;
        x = ((x & ~m) << 1) | (x & m);
    }
    return x;
}

// fused U = Rz*Ry*Rx pair update
__device__ __forceinline__ void apply_u(float2& a0r, float2& a1r,
                                        cplx u00, cplx u01, cplx u10, cplx u11) {
    float2 a0 = a0r, a1 = a1r, b0, b1;
    b0.x = u00.re*a0.x - u00.im*a0.y + u01.re*a1.x - u01.im*a1.y;
    b0.y = u00.re*a0.y + u00.im*a0.x + u01.re*a1.y + u01.im*a1.x;
    b1.x = u10.re*a0.x - u10.im*a0.y + u11.re*a1.x - u11.im*a1.y;
    b1.y = u10.re*a0.y + u10.im*a0.x + u11.re*a1.y + u11.im*a1.x;
    a0r = b0; a1r = b1;
}

template<int NB>   // NB fused-1q gates on NB qubits; 2^NB amps per group
__device__ __forceinline__ void oneq_pass(float2* st, const float2* gcs, int tid,
                                          int pb, const unsigned char* bits) {
    int p[NB], s[NB];
    #pragma unroll
    for (int j = 0; j < NB; ++j) { p[j] = bits[j]; s[j] = bits[j]; }
    sortbits<NB>(s);
    constexpr int GPT = 16 >> NB;
    #pragma unroll
    for (int h = 0; h < GPT; ++h) {
        const int g = tid + h * 1024;
        const int base = expand<NB>(g, s);
        float2 v[1 << NB];
        #pragma unroll
        for (int m = 0; m < (1 << NB); ++m) {
            int off = 0;
            #pragma unroll
            for (int j = 0; j < NB; ++j) off |= ((m >> (NB-1-j)) & 1) << p[j];
            v[m] = st[SWZ(base | off)];
        }
        #pragma unroll
        for (int j = 0; j < NB; ++j) {
            const float2 X = gcs[pb + 3*j], Y = gcs[pb + 3*j + 1], Z = gcs[pb + 3*j + 2];
            const float cx = X.x, sx = X.y, cy = Y.x, sy = Y.y, cz = Z.x, sz = Z.y;
            cplx m00{ cy*cx,  sy*sx }, m01{ -sy*cx, -cy*sx };
            cplx m10{ sy*cx, -cy*sx }, m11{  cy*cx, -sy*sx };
            cplx z0{ cz, -sz }, z1{ cz, sz };
            cplx u00 = cmul(z0, m00), u01 = cmul(z0, m01);
            cplx u10 = cmul(z1, m10), u11 = cmul(z1, m11);
            #pragma unroll
            for (int m = 0; m < (1 << NB); ++m) {
                if (m & (1 << (NB-1-j))) continue;
                apply_u(v[m], v[m | (1 << (NB-1-j))], u00, u01, u10, u11);
            }
        }
        #pragma unroll
        for (int m = 0; m < (1 << NB); ++m) {
            int off = 0;
            #pragma unroll
            for (int j = 0; j < NB; ++j) off |= ((m >> (NB-1-j)) & 1) << p[j];
            st[SWZ(base | off)] = v[m];
        }
    }
}

template<int NG>   // NG sequential CRX gates over NB=NG+1 qubits
__device__ __forceinline__ void chain_pass(float2* st, const float2* gcs, int tid,
                                           int pb, const unsigned char* bits) {
    constexpr int NB = NG + 1;
    int p[NB], s[NB];
    #pragma unroll
    for (int j = 0; j < NB; ++j) { p[j] = bits[j]; s[j] = bits[j]; }
    sortbits<NB>(s);
    constexpr int GPT = 16 >> NB;
    #pragma unroll
    for (int h = 0; h < GPT; ++h) {
        const int g = tid + h * 1024;
        const int base = expand<NB>(g, s);
        float2 v[1 << NB];
        #pragma unroll
        for (int m = 0; m < (1 << NB); ++m) {
            int off = 0;
            #pragma unroll
            for (int j = 0; j < NB; ++j) off |= ((m >> (NB-1-j)) & 1) << p[j];
            v[m] = st[SWZ(base | off)];
        }
        #pragma unroll
        for (int j = 0; j < NG; ++j) {      // gate j: control local NB-1-j, target NB-2-j
            const float2 G = gcs[pb + j];
            const float cr = G.x, sr = G.y;
            #pragma unroll
            for (int m = 0; m < (1 << NB); ++m) {
                if (!(m & (1 << (NB-1-j)))) continue;   // control = 1
                if (m & (1 << (NB-2-j))) continue;       // target  = 0
                const int m1 = m | (1 << (NB-2-j));
                float2 a0 = v[m], a1 = v[m1];
                v[m]  = make_float2(cr*a0.x + sr*a1.y, cr*a0.y - sr*a1.x);
                v[m1] = make_float2(cr*a1.x + sr*a0.y, cr*a1.y - sr*a0.x);
            }
        }
        #pragma unroll
        for (int m = 0; m < (1 << NB); ++m) {
            int off = 0;
            #pragma unroll
            for (int j = 0; j < NB; ++j) off |= ((m >> (NB-1-j)) & 1) << p[j];
            st[SWZ(base | off)] = v[m];
        }
    }
}

__global__ __launch_bounds__(THREADS)
void qsim_kernel(const float* __restrict__ params,
                 unsigned int* __restrict__ out_u32) {
    __shared__ float2 st[NSTATE];      // 128 KiB (swizzled layout)
    __shared__ float2 gcs[NPARAMS];

    const int b   = blockIdx.x;
    const int tid = threadIdx.x;

    if (tid < NPARAMS) {
        float s, c;
        sincosf(0.5f * params[b * NPARAMS + tid], &s, &c);
        gcs[tid] = make_float2(c, s);
    }
    for (int k = tid; k < NSTATE; k += THREADS)
        st[k] = make_float2(k == 0 ? 1.f : 0.f, 0.f);   // SWZ(0)=0

    for (int layer = 0; layer < 2; ++layer) {
        const int L = layer * 70;
        for (int pi = 0; pi < 14; ++pi) {
            __syncthreads();
            const Pass ps = g_passes[pi];
            const int pb = L + ps.pb;
            if (ps.type == 0) {
                if (ps.n == 4) oneq_pass<4>(st, gcs, tid, pb, ps.bits);
                else           oneq_pass<2>(st, gcs, tid, pb, ps.bits);
            } else {
                if (ps.n == 3) chain_pass<3>(st, gcs, tid, pb, ps.bits);
                else           chain_pass<2>(st, gcs, tid, pb, ps.bits);
            }
        }
    }
    __syncthreads();

    // ---- epilogue: amp k -> word (im | re<<16), coalesced ----
    unsigned int* ob = out_u32 + (size_t)b * NSTATE;
    #pragma unroll
    for (int j = 0; j < 16; ++j) {
        const int k = tid + j * 1024;
        const float2 f = st[SWZ(k)];
        ob[k] = f2bf(f.y) | (f2bf(f.x) << 16);
    }
}

extern "C" void kernel_launch(void* const* d_in, const int* in_sizes, int n_in,
                              void* d_out, int out_size, void* d_ws, size_t ws_size,
                              hipStream_t stream) {
    const float* params = (const float*)d_in[0];
    unsigned int* out = (unsigned int*)d_out;
    qsim_kernel<<<BATCH, THREADS, 0, stream>>>(params, out);
}

// Round 28
// 94.422 us; speedup vs baseline: 1.1892x; 1.1145x over previous
//
#include <hip/hip_runtime.h>
#include <math.h>

constexpr int NQ      = 14;
constexpr int NSTATE  = 1 << 14;    // 16384
constexpr int NPARAMS = 140;
constexpr int BATCH   = 128;
constexpr int THREADS = 1024;

struct cplx { float re, im; };
__device__ __forceinline__ cplx cmul(cplx a, cplx b) {
    return { a.re*b.re - a.im*b.im, a.re*b.im + a.im*b.re };
}
__device__ __forceinline__ unsigned int f2bf(float f) {
    union { float f; unsigned int u; } v; v.f = f;
    return (v.u + 0x7FFFu + ((v.u >> 16) & 1u)) >> 16;
}
// global LDS index swizzle: XOR bits 5-8 into bits 1-4 (bijective involution).
__device__ __forceinline__ int SWZ(int i) { return i ^ (((i >> 5) & 0xF) << 1); }

// ---- compile-time pass schedule (verified in R27) ----
// type 0 = ONEQ (n fused-1q gates), type 1 = CHAIN (n sequential CRX gates, n+1 qubits)
struct Pass { int type, n, pb, b0, b1, b2, b3; };
constexpr Pass PASSES[14] = {
    {0,4,0,  13,12,11,10},   // 1q q0-q3
    {0,4,12, 9,8,7,6},       // 1q q4-q7
    {0,4,24, 5,4,3,2},       // 1q q8-q11
    {0,2,36, 1,0,0,0},       // 1q q12,q13
    {1,3,42, 13,12,11,10},   // asc CRX (0,1),(1,2),(2,3)
    {1,3,45, 10,9,8,7},      // asc (3,4),(4,5),(5,6)
    {1,3,48, 7,6,5,4},       // asc (6,7),(7,8),(8,9)
    {1,3,51, 4,3,2,1},       // asc (9,10),(10,11),(11,12)
    {1,2,54, 1,0,13,0},      // asc (12,13),(13,0)
    {1,3,56, 0,1,2,3},       // desc (13,12),(12,11),(11,10)
    {1,3,59, 3,4,5,6},       // desc (10,9),(9,8),(8,7)
    {1,3,62, 6,7,8,9},       // desc (7,6),(6,5),(5,4)
    {1,3,65, 9,10,11,12},    // desc (4,3),(3,2),(2,1)
    {1,2,68, 12,13,0,0},     // desc (1,0),(0,13)
};

struct Sorted { int v[4]; };
constexpr Sorted sort4(int a, int b, int c, int d) {
    Sorted s{{a, b, c, d}};
    for (int i = 0; i < 4; ++i)
        for (int j = 0; j < 3; ++j)
            if (s.v[j] > s.v[j+1]) { int t = s.v[j]; s.v[j] = s.v[j+1]; s.v[j+1] = t; }
    return s;
}
constexpr int offof(int m, int NB, int b0, int b1, int b2, int b3) {
    const int P[4] = {b0, b1, b2, b3};
    int off = 0;
    for (int j = 0; j < NB; ++j) off |= ((m >> (NB-1-j)) & 1) << P[j];
    return off;
}

__device__ __forceinline__ void apply_u(float2& a0r, float2& a1r,
                                        cplx u00, cplx u01, cplx u10, cplx u11) {
    float2 a0 = a0r, a1 = a1r, b0, b1;
    b0.x = u00.re*a0.x - u00.im*a0.y + u01.re*a1.x - u01.im*a1.y;
    b0.y = u00.re*a0.y + u00.im*a0.x + u01.re*a1.y + u01.im*a1.x;
    b1.x = u10.re*a0.x - u10.im*a0.y + u11.re*a1.x - u11.im*a1.y;
    b1.y = u10.re*a0.y + u10.im*a0.x + u11.re*a1.y + u11.im*a1.x;
    a0r = b0; a1r = b1;
}

template<int PI>
__device__ __forceinline__ void do_pass(float2* st, const float2* gcs, int tid, int L) {
    constexpr Pass ps = PASSES[PI];
    constexpr int NG = ps.n;
    constexpr int NB = (ps.type == 0) ? ps.n : ps.n + 1;
    constexpr Sorted S = sort4(ps.b0, ps.b1, (NB > 2 ? ps.b2 : 99), (NB > 3 ? ps.b3 : 99));
    constexpr int GPT = 16 >> NB;   // groups per thread
    const int pb = L + ps.pb;

    #pragma unroll
    for (int h = 0; h < GPT; ++h) {
        int base = tid + h * 1024;
        #pragma unroll
        for (int j = 0; j < NB; ++j) {               // expand: insert 0 at sorted bits
            const int m = (1 << S.v[j]) - 1;         // compile-time mask
            base = ((base & ~m) << 1) | (base & m);
        }
        float2 v[1 << NB];
        #pragma unroll
        for (int m = 0; m < (1 << NB); ++m)
            v[m] = st[SWZ(base | offof(m, NB, ps.b0, ps.b1, ps.b2, ps.b3))];

        if constexpr (ps.type == 0) {
            #pragma unroll
            for (int j = 0; j < NG; ++j) {
                const float2 X = gcs[pb + 3*j], Y = gcs[pb + 3*j + 1], Z = gcs[pb + 3*j + 2];
                const float cx = X.x, sx = X.y, cy = Y.x, sy = Y.y, cz = Z.x, sz = Z.y;
                cplx m00{ cy*cx,  sy*sx }, m01{ -sy*cx, -cy*sx };
                cplx m10{ sy*cx, -cy*sx }, m11{  cy*cx, -sy*sx };
                cplx z0{ cz, -sz }, z1{ cz, sz };
                cplx u00 = cmul(z0, m00), u01 = cmul(z0, m01);
                cplx u10 = cmul(z1, m10), u11 = cmul(z1, m11);
                #pragma unroll
                for (int m = 0; m < (1 << NB); ++m) {
                    if (m & (1 << (NB-1-j))) continue;
                    apply_u(v[m], v[m | (1 << (NB-1-j))], u00, u01, u10, u11);
                }
            }
        } else {
            #pragma unroll
            for (int j = 0; j < NG; ++j) {   // gate j: control local NB-1-j, target NB-2-j
                const float2 G = gcs[pb + j];
                const float cr = G.x, sr = G.y;
                #pragma unroll
                for (int m = 0; m < (1 << NB); ++m) {
                    if (!(m & (1 << (NB-1-j)))) continue;   // control = 1
                    if (m & (1 << (NB-2-j))) continue;      // target  = 0
                    const int m1 = m | (1 << (NB-2-j));
                    float2 a0 = v[m], a1 = v[m1];
                    v[m]  = make_float2(cr*a0.x + sr*a1.y, cr*a0.y - sr*a1.x);
                    v[m1] = make_float2(cr*a1.x + sr*a0.y, cr*a1.y - sr*a0.x);
                }
            }
        }

        #pragma unroll
        for (int m = 0; m < (1 << NB); ++m)
            st[SWZ(base | offof(m, NB, ps.b0, ps.b1, ps.b2, ps.b3))] = v[m];
    }
}

template<int PI>
struct RunPasses {
    static __device__ __forceinline__ void go(float2* st, const float2* gcs, int tid, int L) {
        __syncthreads();
        do_pass<PI>(st, gcs, tid, L);
        RunPasses<PI + 1>::go(st, gcs, tid, L);
    }
};
template<> struct RunPasses<14> {
    static __device__ __forceinline__ void go(float2*, const float2*, int, int) {}
};

__global__ __launch_bounds__(THREADS)
void qsim_kernel(const float* __restrict__ params,
                 unsigned int* __restrict__ out_u32) {
    __shared__ float2 st[NSTATE];      // 128 KiB (swizzled layout)
    __shared__ float2 gcs[NPARAMS];

    const int b   = blockIdx.x;
    const int tid = threadIdx.x;

    if (tid < NPARAMS) {
        float s, c;
        sincosf(0.5f * params[b * NPARAMS + tid], &s, &c);
        gcs[tid] = make_float2(c, s);
    }
    for (int k = tid; k < NSTATE; k += THREADS)
        st[k] = make_float2(k == 0 ? 1.f : 0.f, 0.f);   // SWZ(0)=0

    #pragma unroll 1
    for (int layer = 0; layer < 2; ++layer)
        RunPasses<0>::go(st, gcs, tid, layer * 70);
    __syncthreads();

    // ---- epilogue: amp k -> word (im | re<<16), coalesced ----
    unsigned int* ob = out_u32 + (size_t)b * NSTATE;
    #pragma unroll
    for (int j = 0; j < 16; ++j) {
        const int k = tid + j * 1024;
        const float2 f = st[SWZ(k)];
        ob[k] = f2bf(f.y) | (f2bf(f.x) << 16);
    }
}

extern "C" void kernel_launch(void* const* d_in, const int* in_sizes, int n_in,
                              void* d_out, int out_size, void* d_ws, size_t ws_size,
                              hipStream_t stream) {
    const float* params = (const float*)d_in[0];
    unsigned int* out = (unsigned int*)d_out;
    qsim_kernel<<<BATCH, THREADS, 0, stream>>>(params, out);
}

// Round 29
// 91.707 us; speedup vs baseline: 1.2245x; 1.0296x over previous
//
#include <hip/hip_runtime.h>
#include <math.h>

constexpr int NQ      = 14;
constexpr int NSTATE  = 1 << 14;    // 16384
constexpr int NPARAMS = 140;
constexpr int BATCH   = 128;
constexpr int THREADS = 1024;

struct cplx { float re, im; };
__device__ __forceinline__ cplx cmul(cplx a, cplx b) {
    return { a.re*b.re - a.im*b.im, a.re*b.im + a.im*b.re };
}
__device__ __forceinline__ unsigned int f2bf(float f) {
    union { float f; unsigned int u; } v; v.f = f;
    return (v.u + 0x7FFFu + ((v.u >> 16) & 1u)) >> 16;
}
// global LDS index swizzle: XOR bits 5-8 into bits 1-4 (bijective involution).
__device__ __forceinline__ int SWZ(int i) { return i ^ (((i >> 5) & 0xF) << 1); }
__device__ __forceinline__ void fence() { __builtin_amdgcn_sched_barrier(0); }

// ---- compile-time pass schedule, NB<=3 (v[8] max) ----
// type 0 = ONEQ (n fused-1q gates on n qubits), type 1 = CHAIN (n CRX gates, n+1 qubits)
struct Pass { int type, n, pb, b0, b1, b2; };
constexpr Pass PASSES[19] = {
    {0,3,0,  13,12,11},   // 1q q0-q2
    {0,3,9,  10,9,8},     // 1q q3-q5
    {0,3,18, 7,6,5},      // 1q q6-q8
    {0,3,27, 4,3,2},      // 1q q9-q11
    {0,2,36, 1,0,0},      // 1q q12,q13
    {1,2,42, 13,12,11},   // asc (0,1),(1,2)
    {1,2,44, 11,10,9},    // asc (2,3),(3,4)
    {1,2,46, 9,8,7},      // asc (4,5),(5,6)
    {1,2,48, 7,6,5},      // asc (6,7),(7,8)
    {1,2,50, 5,4,3},      // asc (8,9),(9,10)
    {1,2,52, 3,2,1},      // asc (10,11),(11,12)
    {1,2,54, 1,0,13},     // asc (12,13),(13,0)
    {1,2,56, 0,1,2},      // desc (13,12),(12,11)
    {1,2,58, 2,3,4},      // desc (11,10),(10,9)
    {1,2,60, 4,5,6},      // desc (9,8),(8,7)
    {1,2,62, 6,7,8},      // desc (7,6),(6,5)
    {1,2,64, 8,9,10},     // desc (5,4),(4,3)
    {1,2,66, 10,11,12},   // desc (3,2),(2,1)
    {1,2,68, 12,13,0},    // desc (1,0),(0,13)
};

struct Sorted { int v[3]; };
constexpr Sorted sort3(int a, int b, int c) {
    Sorted s{{a, b, c}};
    for (int i = 0; i < 3; ++i)
        for (int j = 0; j < 2; ++j)
            if (s.v[j] > s.v[j+1]) { int t = s.v[j]; s.v[j] = s.v[j+1]; s.v[j+1] = t; }
    return s;
}
constexpr int offof(int m, int NB, int b0, int b1, int b2) {
    const int P[3] = {b0, b1, b2};
    int off = 0;
    for (int j = 0; j < NB; ++j) off |= ((m >> (NB-1-j)) & 1) << P[j];
    return off;
}

__device__ __forceinline__ void apply_u(float2& a0r, float2& a1r,
                                        cplx u00, cplx u01, cplx u10, cplx u11) {
    float2 a0 = a0r, a1 = a1r, b0, b1;
    b0.x = u00.re*a0.x - u00.im*a0.y + u01.re*a1.x - u01.im*a1.y;
    b0.y = u00.re*a0.y + u00.im*a0.x + u01.re*a1.y + u01.im*a1.x;
    b1.x = u10.re*a0.x - u10.im*a0.y + u11.re*a1.x - u11.im*a1.y;
    b1.y = u10.re*a0.y + u10.im*a0.x + u11.re*a1.y + u11.im*a1.x;
    a0r = b0; a1r = b1;
}

template<int PI>
__device__ __forceinline__ void do_pass(float2* st, const float2* gcs, int tid, int L) {
    constexpr Pass ps = PASSES[PI];
    constexpr int NG = ps.n;
    constexpr int NB = (ps.type == 0) ? ps.n : ps.n + 1;
    constexpr Sorted S = sort3(ps.b0, ps.b1, (NB > 2 ? ps.b2 : 99));
    constexpr int GPT = 16 >> NB;   // groups per thread (2 for NB=3, 4 for NB=2)
    const int pb = L + ps.pb;

    #pragma unroll 1
    for (int h = 0; h < GPT; ++h) {
        int base = tid + (h << 10);
        #pragma unroll
        for (int j = 0; j < NB; ++j) {               // insert 0 at sorted bit positions
            const int m = (1 << S.v[j]) - 1;         // compile-time mask
            base = ((base & ~m) << 1) | (base & m);
        }
        float2 v[1 << NB];
        #pragma unroll
        for (int m = 0; m < (1 << NB); ++m)
            v[m] = st[SWZ(base | offof(m, NB, ps.b0, ps.b1, ps.b2))];

        if constexpr (ps.type == 0) {
            #pragma unroll
            for (int j = 0; j < NG; ++j) {
                const float2 X = gcs[pb + 3*j], Y = gcs[pb + 3*j + 1], Z = gcs[pb + 3*j + 2];
                const float cx = X.x, sx = X.y, cy = Y.x, sy = Y.y, cz = Z.x, sz = Z.y;
                cplx m00{ cy*cx,  sy*sx }, m01{ -sy*cx, -cy*sx };
                cplx m10{ sy*cx, -cy*sx }, m11{  cy*cx, -sy*sx };
                cplx z0{ cz, -sz }, z1{ cz, sz };
                cplx u00 = cmul(z0, m00), u01 = cmul(z0, m01);
                cplx u10 = cmul(z1, m10), u11 = cmul(z1, m11);
                #pragma unroll
                for (int m = 0; m < (1 << NB); ++m) {
                    if (m & (1 << (NB-1-j))) continue;
                    apply_u(v[m], v[m | (1 << (NB-1-j))], u00, u01, u10, u11);
                }
            }
        } else {
            #pragma unroll
            for (int j = 0; j < NG; ++j) {   // gate j: control local NB-1-j, target NB-2-j
                const float2 G = gcs[pb + j];
                const float cr = G.x, sr = G.y;
                #pragma unroll
                for (int m = 0; m < (1 << NB); ++m) {
                    if (!(m & (1 << (NB-1-j)))) continue;   // control = 1
                    if (m & (1 << (NB-2-j))) continue;      // target  = 0
                    const int m1 = m | (1 << (NB-2-j));
                    float2 a0 = v[m], a1 = v[m1];
                    v[m]  = make_float2(cr*a0.x + sr*a1.y, cr*a0.y - sr*a1.x);
                    v[m1] = make_float2(cr*a1.x + sr*a0.y, cr*a1.y - sr*a0.x);
                }
            }
        }

        #pragma unroll
        for (int m = 0; m < (1 << NB); ++m)
            st[SWZ(base | offof(m, NB, ps.b0, ps.b1, ps.b2))] = v[m];
        fence();                                      // cap live ranges per subgroup
    }
}

template<int PI>
struct RunPasses {
    static __device__ __forceinline__ void go(float2* st, const float2* gcs, int tid, int L) {
        __syncthreads();
        do_pass<PI>(st, gcs, tid, L);
        fence();
        RunPasses<PI + 1>::go(st, gcs, tid, L);
    }
};
template<> struct RunPasses<19> {
    static __device__ __forceinline__ void go(float2*, const float2*, int, int) {}
};

__global__ __launch_bounds__(THREADS)
void qsim_kernel(const float* __restrict__ params,
                 unsigned int* __restrict__ out_u32) {
    __shared__ float2 st[NSTATE];      // 128 KiB (swizzled layout)
    __shared__ float2 gcs[NPARAMS];

    const int b   = blockIdx.x;
    const int tid = threadIdx.x;

    if (tid < NPARAMS) {
        float s, c;
        sincosf(0.5f * params[b * NPARAMS + tid], &s, &c);
        gcs[tid] = make_float2(c, s);
    }
    for (int k = tid; k < NSTATE; k += THREADS)
        st[k] = make_float2(k == 0 ? 1.f : 0.f, 0.f);   // SWZ(0)=0

    #pragma unroll 1
    for (int layer = 0; layer < 2; ++layer)
        RunPasses<0>::go(st, gcs, tid, layer * 70);
    __syncthreads();

    // ---- epilogue: amp k -> word (im | re<<16), coalesced ----
    unsigned int* ob = out_u32 + (size_t)b * NSTATE;
    #pragma unroll
    for (int j = 0; j < 16; ++j) {
        const int k = tid + j * 1024;
        const float2 f = st[SWZ(k)];
        ob[k] = f2bf(f.y) | (f2bf(f.x) << 16);
    }
}

extern "C" void kernel_launch(void* const* d_in, const int* in_sizes, int n_in,
                              void* d_out, int out_size, void* d_ws, size_t ws_size,
                              hipStream_t stream) {
    const float* params = (const float*)d_in[0];
    unsigned int* out = (unsigned int*)d_out;
    qsim_kernel<<<BATCH, THREADS, 0, stream>>>(params, out);
}

// Round 30
// 63.510 us; speedup vs baseline: 1.7681x; 1.4440x over previous
//
#include <hip/hip_runtime.h>
#include <math.h>

constexpr int NQ      = 14;
constexpr int NSTATE  = 1 << 14;    // 16384 amps
constexpr int NF4     = NSTATE / 2; // 8192 float4 (amp pair) elements
constexpr int NPARAMS = 140;
constexpr int BATCH   = 128;
constexpr int THREADS = 1024;

struct cplx { float re, im; };
__device__ __forceinline__ cplx cmul(cplx a, cplx b) {
    return { a.re*b.re - a.im*b.im, a.re*b.im + a.im*b.re };
}
__device__ __forceinline__ unsigned int f2bf(float f) {
    union { float f; unsigned int u; } v; v.f = f;
    return (v.u + 0x7FFFu + ((v.u >> 16) & 1u)) >> 16;
}
// float4-index swizzle: XOR bits 3-5 into bits 0-2 (involution; conflict-free
// for all base patterns in this schedule — verified per 8-lane cycle groups).
__device__ __forceinline__ int SWZ4(int f) { return f ^ ((f >> 3) & 7); }

// one amp-pair update: (ax,ay) = lo amp, (bx,by) = hi amp
__device__ __forceinline__ void u_half(float& ax, float& ay, float& bx, float& by,
                                       cplx u00, cplx u01, cplx u10, cplx u11) {
    float a0x = ax, a0y = ay, a1x = bx, a1y = by;
    ax = u00.re*a0x - u00.im*a0y + u01.re*a1x - u01.im*a1y;
    ay = u00.re*a0y + u00.im*a0x + u01.re*a1y + u01.im*a1x;
    bx = u10.re*a0x - u10.im*a0y + u11.re*a1x - u11.im*a1y;
    by = u10.re*a0y + u10.im*a0x + u11.re*a1y + u11.im*a1x;
}
__device__ __forceinline__ void crx_half(float& ax, float& ay, float& bx, float& by,
                                         float cr, float sr) {
    float a0x = ax, a0y = ay, a1x = bx, a1y = by;
    ax = cr*a0x + sr*a1y;  ay = cr*a0y - sr*a1x;
    bx = cr*a1x + sr*a0y;  by = cr*a1y - sr*a0x;
}

// gate: type 0 = fused 1q on state bit t; type 1 = CRX control bit c -> target bit t.
// bit 0 = intra-float4 (z,w half is bit0=1).
struct G  { int type, pb, c, t; };
struct P2 { int nb, b0, b1, b2, ng; G g0, g1, g2; };

// 18 passes/layer; gates appear in exact pb (reference) order.
constexpr P2 PS[18] = {
    {3,13,12,11, 3, {0,0,0,13},  {0,3,0,12},  {0,6,0,11}},   // 1q q0,q1,q2
    {3,10,9,8,   3, {0,9,0,10},  {0,12,0,9},  {0,15,0,8}},   // 1q q3,q4,q5
    {3,7,6,5,    3, {0,18,0,7},  {0,21,0,6},  {0,24,0,5}},   // 1q q6,q7,q8
    {3,4,3,2,    3, {0,27,0,4},  {0,30,0,3},  {0,33,0,2}},   // 1q q9,q10,q11
    {1,1,0,0,    2, {0,36,0,1},  {0,39,0,0},  {0,0,0,0}},    // 1q q12,q13
    {3,13,12,11, 2, {1,42,13,12},{1,43,12,11},{0,0,0,0}},    // asc (0,1),(1,2)
    {3,11,10,9,  2, {1,44,11,10},{1,45,10,9}, {0,0,0,0}},    // asc (2,3),(3,4)
    {3,9,8,7,    2, {1,46,9,8},  {1,47,8,7},  {0,0,0,0}},    // asc (4,5),(5,6)
    {3,7,6,5,    2, {1,48,7,6},  {1,49,6,5},  {0,0,0,0}},    // asc (6,7),(7,8)
    {3,5,4,3,    2, {1,50,5,4},  {1,51,4,3},  {0,0,0,0}},    // asc (8,9),(9,10)
    {3,3,2,1,    3, {1,52,3,2},  {1,53,2,1},  {1,54,1,0}},   // asc (10,11),(11,12),(12,13)
    {3,13,2,1,   3, {1,55,0,13}, {1,56,0,1},  {1,57,1,2}},   // asc (13,0); desc (13,12),(12,11)
    {3,4,3,2,    2, {1,58,2,3},  {1,59,3,4},  {0,0,0,0}},    // desc (11,10),(10,9)
    {3,6,5,4,    2, {1,60,4,5},  {1,61,5,6},  {0,0,0,0}},    // desc (9,8),(8,7)
    {3,8,7,6,    2, {1,62,6,7},  {1,63,7,8},  {0,0,0,0}},    // desc (7,6),(6,5)
    {3,10,9,8,   2, {1,64,8,9},  {1,65,9,10}, {0,0,0,0}},    // desc (5,4),(4,3)
    {3,12,11,10, 2, {1,66,10,11},{1,67,11,12},{0,0,0,0}},    // desc (3,2),(2,1)
    {2,13,12,0,  2, {1,68,12,13},{1,69,13,0}, {0,0,0,0}},    // desc (1,0),(0,13)
};

struct Sorted { int v[3]; };
constexpr Sorted sort3(int a, int b, int c) {
    Sorted s{{a, b, c}};
    for (int i = 0; i < 3; ++i)
        for (int j = 0; j < 2; ++j)
            if (s.v[j] > s.v[j+1]) { int t = s.v[j]; s.v[j] = s.v[j+1]; s.v[j+1] = t; }
    return s;
}
// float4-space offset of local index m (local MSB = b0)
constexpr int off4(int m, int nb, int b0, int b1, int b2) {
    const int B[3] = { b0 - 1, b1 - 1, b2 - 1 };
    int off = 0;
    for (int j = 0; j < nb; ++j) off |= ((m >> (nb-1-j)) & 1) << B[j];
    return off;
}
constexpr int locbit(int b, int b0, int b1, int b2, int nb) {
    return (b == b0) ? (1 << (nb-1)) : (b == b1) ? (1 << (nb-2)) : (1 << (nb-3));
}

template<int PI, int GI, int VN>
__device__ __forceinline__ void apply_g(float4 (&v)[VN], const float2* gcs, int L) {
    constexpr P2 ps = PS[PI];
    constexpr G  g  = (GI == 0) ? ps.g0 : (GI == 1) ? ps.g1 : ps.g2;
    const int pb = L + g.pb;
    if constexpr (g.type == 0) {
        const float2 X = gcs[pb], Y = gcs[pb+1], Z = gcs[pb+2];
        const float cx = X.x, sx = X.y, cy = Y.x, sy = Y.y, cz = Z.x, sz = Z.y;
        cplx m00{ cy*cx,  sy*sx }, m01{ -sy*cx, -cy*sx };
        cplx m10{ sy*cx, -cy*sx }, m11{  cy*cx, -sy*sx };
        cplx z0{ cz, -sz }, z1{ cz, sz };
        cplx u00 = cmul(z0, m00), u01 = cmul(z0, m01);
        cplx u10 = cmul(z1, m10), u11 = cmul(z1, m11);
        if constexpr (g.t == 0) {
            #pragma unroll
            for (int m = 0; m < VN; ++m)
                u_half(v[m].x, v[m].y, v[m].z, v[m].w, u00, u01, u10, u11);
        } else {
            constexpr int tb = locbit(g.t, ps.b0, ps.b1, ps.b2, ps.nb);
            #pragma unroll
            for (int m = 0; m < VN; ++m) {
                if (m & tb) continue;
                u_half(v[m].x, v[m].y, v[m|tb].x, v[m|tb].y, u00, u01, u10, u11);
                u_half(v[m].z, v[m].w, v[m|tb].z, v[m|tb].w, u00, u01, u10, u11);
            }
        }
    } else {
        const float2 C = gcs[pb];
        const float cr = C.x, sr = C.y;
        if constexpr (g.c == 0) {            // control = bit 0: zw halves only
            constexpr int tb = locbit(g.t, ps.b0, ps.b1, ps.b2, ps.nb);
            #pragma unroll
            for (int m = 0; m < VN; ++m) {
                if (m & tb) continue;
                crx_half(v[m].z, v[m].w, v[m|tb].z, v[m|tb].w, cr, sr);
            }
        } else if constexpr (g.t == 0) {     // target = bit 0: intra-float4
            constexpr int cb = locbit(g.c, ps.b0, ps.b1, ps.b2, ps.nb);
            #pragma unroll
            for (int m = 0; m < VN; ++m) {
                if (!(m & cb)) continue;
                crx_half(v[m].x, v[m].y, v[m].z, v[m].w, cr, sr);
            }
        } else {
            constexpr int cb = locbit(g.c, ps.b0, ps.b1, ps.b2, ps.nb);
            constexpr int tb = locbit(g.t, ps.b0, ps.b1, ps.b2, ps.nb);
            #pragma unroll
            for (int m = 0; m < VN; ++m) {
                if (!(m & cb) || (m & tb)) continue;
                crx_half(v[m].x, v[m].y, v[m|tb].x, v[m|tb].y, cr, sr);
                crx_half(v[m].z, v[m].w, v[m|tb].z, v[m|tb].w, cr, sr);
            }
        }
    }
}

template<int PI>
__device__ __forceinline__ void do_pass(float4* st4, const float2* gcs, int tid, int L) {
    constexpr P2 ps = PS[PI];
    constexpr int NB  = ps.nb;
    constexpr int VN  = 1 << NB;
    constexpr int GPT = 8 >> NB;
    constexpr Sorted S = sort3(ps.b0 - 1, (NB > 1 ? ps.b1 - 1 : 99), (NB > 2 ? ps.b2 - 1 : 99));

    #pragma unroll
    for (int h = 0; h < GPT; ++h) {
        int base = tid + (h << 10);
        #pragma unroll
        for (int j = 0; j < NB; ++j) {           // insert 0 at sorted float4-bits
            const int m = (1 << S.v[j]) - 1;
            base = ((base & ~m) << 1) | (base & m);
        }
        float4 v[VN];
        #pragma unroll
        for (int m = 0; m < VN; ++m)
            v[m] = st4[SWZ4(base | off4(m, NB, ps.b0, ps.b1, ps.b2))];

        apply_g<PI, 0, VN>(v, gcs, L);
        if constexpr (ps.ng > 1) apply_g<PI, 1, VN>(v, gcs, L);
        if constexpr (ps.ng > 2) apply_g<PI, 2, VN>(v, gcs, L);

        #pragma unroll
        for (int m = 0; m < VN; ++m)
            st4[SWZ4(base | off4(m, NB, ps.b0, ps.b1, ps.b2))] = v[m];
        __builtin_amdgcn_sched_barrier(0);
    }
}

template<int PI>
struct RunPasses {
    static __device__ __forceinline__ void go(float4* st4, const float2* gcs, int tid, int L) {
        __syncthreads();
        do_pass<PI>(st4, gcs, tid, L);
        RunPasses<PI + 1>::go(st4, gcs, tid, L);
    }
};
template<> struct RunPasses<18> {
    static __device__ __forceinline__ void go(float4*, const float2*, int, int) {}
};

__global__ __launch_bounds__(THREADS)
void qsim_kernel(const float* __restrict__ params,
                 unsigned int* __restrict__ out_u32) {
    __shared__ float4 st4[NF4];        // 128 KiB; element f = amps (2f, 2f+1), swizzled
    __shared__ float2 gcs[NPARAMS];

    const int b   = blockIdx.x;
    const int tid = threadIdx.x;

    if (tid < NPARAMS) {
        float s, c;
        sincosf(0.5f * params[b * NPARAMS + tid], &s, &c);
        gcs[tid] = make_float2(c, s);
    }
    for (int k = tid; k < NF4; k += THREADS)
        st4[k] = make_float4(k == 0 ? 1.f : 0.f, 0.f, 0.f, 0.f);   // SWZ4(0)=0

    #pragma unroll 1
    for (int layer = 0; layer < 2; ++layer)
        RunPasses<0>::go(st4, gcs, tid, layer * 70);
    __syncthreads();

    // ---- epilogue: float4 f -> words 2f (im|re), 2f+1 (im|re); coalesced uint2 ----
    uint2* ob = (uint2*)(out_u32 + (size_t)b * NSTATE);
    #pragma unroll
    for (int j = 0; j < 8; ++j) {
        const int f = tid + j * 1024;
        const float4 F = st4[SWZ4(f)];
        uint2 w;
        w.x = f2bf(F.y) | (f2bf(F.x) << 16);   // amp 2f   : low=Im, high=Re
        w.y = f2bf(F.w) | (f2bf(F.z) << 16);   // amp 2f+1
        ob[f] = w;
    }
}

extern "C" void kernel_launch(void* const* d_in, const int* in_sizes, int n_in,
                              void* d_out, int out_size, void* d_ws, size_t ws_size,
                              hipStream_t stream) {
    const float* params = (const float*)d_in[0];
    unsigned int* out = (unsigned int*)d_out;
    qsim_kernel<<<BATCH, THREADS, 0, stream>>>(params, out);
}

// Round 31
// 60.317 us; speedup vs baseline: 1.8617x; 1.0529x over previous
//
#include <hip/hip_runtime.h>
#include <math.h>

constexpr int NQ      = 14;
constexpr int NSTATE  = 1 << 14;    // 16384 amps
constexpr int NF4     = NSTATE / 2; // 8192 float4 (amp pair) elements
constexpr int NPARAMS = 140;
constexpr int BATCH   = 128;
constexpr int THREADS = 1024;

__device__ __forceinline__ unsigned int f2bf(float f) {
    union { float f; unsigned int u; } v; v.f = f;
    return (v.u + 0x7FFFu + ((v.u >> 16) & 1u)) >> 16;
}
// float4-index swizzle: XOR bits 3-5 into bits 0-2 (involution).
__device__ __forceinline__ int SWZ4(int f) { return f ^ ((f >> 3) & 7); }

// SU(2) pair update: b0 = u*a0 + v*a1 ; b1 = -conj(v)*a0 + conj(u)*a1
__device__ __forceinline__ void u_half2(float& ax, float& ay, float& bx, float& by,
                                        float ur, float ui, float vr, float vi) {
    float a0x = ax, a0y = ay, a1x = bx, a1y = by;
    ax =  ur*a0x - ui*a0y + vr*a1x - vi*a1y;
    ay =  ur*a0y + ui*a0x + vr*a1y + vi*a1x;
    bx = -vr*a0x - vi*a0y + ur*a1x + ui*a1y;
    by = -vr*a0y + vi*a0x + ur*a1y - ui*a1x;
}
__device__ __forceinline__ void crx_half(float& ax, float& ay, float& bx, float& by,
                                         float cr, float sr) {
    float a0x = ax, a0y = ay, a1x = bx, a1y = by;
    ax = cr*a0x + sr*a1y;  ay = cr*a0y - sr*a1x;
    bx = cr*a1x + sr*a0y;  by = cr*a1y - sr*a0x;
}

// gate: type 0 = fused 1q on state bit t; type 1 = CRX control bit c -> target bit t.
// bit 0 = intra-float4 (z,w half is bit0=1).
struct G  { int type, pb, c, t; };
struct P2 { int nb, b0, b1, b2, ng; G g0, g1, g2; };

// 18 passes/layer; gates appear in exact pb (reference) order. (verified R30)
constexpr P2 PS[18] = {
    {3,13,12,11, 3, {0,0,0,13},  {0,3,0,12},  {0,6,0,11}},   // 1q q0,q1,q2
    {3,10,9,8,   3, {0,9,0,10},  {0,12,0,9},  {0,15,0,8}},   // 1q q3,q4,q5
    {3,7,6,5,    3, {0,18,0,7},  {0,21,0,6},  {0,24,0,5}},   // 1q q6,q7,q8
    {3,4,3,2,    3, {0,27,0,4},  {0,30,0,3},  {0,33,0,2}},   // 1q q9,q10,q11
    {1,1,0,0,    2, {0,36,0,1},  {0,39,0,0},  {0,0,0,0}},    // 1q q12,q13
    {3,13,12,11, 2, {1,42,13,12},{1,43,12,11},{0,0,0,0}},    // asc (0,1),(1,2)
    {3,11,10,9,  2, {1,44,11,10},{1,45,10,9}, {0,0,0,0}},    // asc (2,3),(3,4)
    {3,9,8,7,    2, {1,46,9,8},  {1,47,8,7},  {0,0,0,0}},    // asc (4,5),(5,6)
    {3,7,6,5,    2, {1,48,7,6},  {1,49,6,5},  {0,0,0,0}},    // asc (6,7),(7,8)
    {3,5,4,3,    2, {1,50,5,4},  {1,51,4,3},  {0,0,0,0}},    // asc (8,9),(9,10)
    {3,3,2,1,    3, {1,52,3,2},  {1,53,2,1},  {1,54,1,0}},   // asc (10,11),(11,12),(12,13)
    {3,13,2,1,   3, {1,55,0,13}, {1,56,0,1},  {1,57,1,2}},   // asc (13,0); desc (13,12),(12,11)
    {3,4,3,2,    2, {1,58,2,3},  {1,59,3,4},  {0,0,0,0}},    // desc (11,10),(10,9)
    {3,6,5,4,    2, {1,60,4,5},  {1,61,5,6},  {0,0,0,0}},    // desc (9,8),(8,7)
    {3,8,7,6,    2, {1,62,6,7},  {1,63,7,8},  {0,0,0,0}},    // desc (7,6),(6,5)
    {3,10,9,8,   2, {1,64,8,9},  {1,65,9,10}, {0,0,0,0}},    // desc (5,4),(4,3)
    {3,12,11,10, 2, {1,66,10,11},{1,67,11,12},{0,0,0,0}},    // desc (3,2),(2,1)
    {2,13,12,0,  2, {1,68,12,13},{1,69,13,0}, {0,0,0,0}},    // desc (1,0),(0,13)
};

struct Sorted { int v[3]; };
constexpr Sorted sort3(int a, int b, int c) {
    Sorted s{{a, b, c}};
    for (int i = 0; i < 3; ++i)
        for (int j = 0; j < 2; ++j)
            if (s.v[j] > s.v[j+1]) { int t = s.v[j]; s.v[j] = s.v[j+1]; s.v[j+1] = t; }
    return s;
}
constexpr int off4(int m, int nb, int b0, int b1, int b2) {
    const int B[3] = { b0 - 1, b1 - 1, b2 - 1 };
    int off = 0;
    for (int j = 0; j < nb; ++j) off |= ((m >> (nb-1-j)) & 1) << B[j];
    return off;
}
constexpr int locbit(int b, int b0, int b1, int b2, int nb) {
    return (b == b0) ? (1 << (nb-1)) : (b == b1) ? (1 << (nb-2)) : (1 << (nb-3));
}
// which v-elements any gate in the pass reads/writes
constexpr int touch_mask(P2 ps) {
    const int VN = 1 << ps.nb;
    const G gs[3] = { ps.g0, ps.g1, ps.g2 };
    int t = 0;
    for (int gi = 0; gi < ps.ng; ++gi) {
        G g = gs[gi];
        if (g.type == 0 || g.c == 0) { t = (1 << VN) - 1; break; }
        int cb = locbit(g.c, ps.b0, ps.b1, ps.b2, ps.nb);
        for (int m = 0; m < VN; ++m) if (m & cb) t |= 1 << m;
    }
    return t;
}

template<int PI, int GI, int VN>
__device__ __forceinline__ void apply_g(float4 (&v)[VN], const float2* gcs, int L) {
    constexpr P2 ps = PS[PI];
    constexpr G  g  = (GI == 0) ? ps.g0 : (GI == 1) ? ps.g1 : ps.g2;
    const int pb = L + g.pb;
    if constexpr (g.type == 0) {
        const float2 X = gcs[pb], Y = gcs[pb+1], Z = gcs[pb+2];
        const float cx = X.x, sx = X.y, cy = Y.x, sy = Y.y, cz = Z.x, sz = Z.y;
        // u00 = z0*(cy*cx + i sy*sx), u01 = z0*(-sy*cx - i cy*sx), z0 = cz - i sz
        const float m0r = cy*cx, m0i = sy*sx, m1r = -sy*cx, m1i = -cy*sx;
        const float ur = cz*m0r + sz*m0i, ui = cz*m0i - sz*m0r;
        const float vr = cz*m1r + sz*m1i, vi = cz*m1i - sz*m1r;
        if constexpr (g.t == 0) {
            #pragma unroll
            for (int m = 0; m < VN; ++m)
                u_half2(v[m].x, v[m].y, v[m].z, v[m].w, ur, ui, vr, vi);
        } else {
            constexpr int tb = locbit(g.t, ps.b0, ps.b1, ps.b2, ps.nb);
            #pragma unroll
            for (int m = 0; m < VN; ++m) {
                if (m & tb) continue;
                u_half2(v[m].x, v[m].y, v[m|tb].x, v[m|tb].y, ur, ui, vr, vi);
                u_half2(v[m].z, v[m].w, v[m|tb].z, v[m|tb].w, ur, ui, vr, vi);
            }
        }
    } else {
        const float2 C = gcs[pb];
        const float cr = C.x, sr = C.y;
        if constexpr (g.c == 0) {            // control = bit 0: zw halves only
            constexpr int tb = locbit(g.t, ps.b0, ps.b1, ps.b2, ps.nb);
            #pragma unroll
            for (int m = 0; m < VN; ++m) {
                if (m & tb) continue;
                crx_half(v[m].z, v[m].w, v[m|tb].z, v[m|tb].w, cr, sr);
            }
        } else if constexpr (g.t == 0) {     // target = bit 0: intra-float4
            constexpr int cb = locbit(g.c, ps.b0, ps.b1, ps.b2, ps.nb);
            #pragma unroll
            for (int m = 0; m < VN; ++m) {
                if (!(m & cb)) continue;
                crx_half(v[m].x, v[m].y, v[m].z, v[m].w, cr, sr);
            }
        } else {
            constexpr int cb = locbit(g.c, ps.b0, ps.b1, ps.b2, ps.nb);
            constexpr int tb = locbit(g.t, ps.b0, ps.b1, ps.b2, ps.nb);
            #pragma unroll
            for (int m = 0; m < VN; ++m) {
                if (!(m & cb) || (m & tb)) continue;
                crx_half(v[m].x, v[m].y, v[m|tb].x, v[m|tb].y, cr, sr);
                crx_half(v[m].z, v[m].w, v[m|tb].z, v[m|tb].w, cr, sr);
            }
        }
    }
}

template<int PI>
__device__ __forceinline__ void do_pass(float4* st4, const float2* gcs, int tid, int L) {
    constexpr P2 ps = PS[PI];
    constexpr int NB  = ps.nb;
    constexpr int VN  = 1 << NB;
    constexpr int GPT = 8 >> NB;
    constexpr int TM  = touch_mask(ps);
    constexpr Sorted S = sort3(ps.b0 - 1, (NB > 1 ? ps.b1 - 1 : 99), (NB > 2 ? ps.b2 - 1 : 99));

    #pragma unroll
    for (int h = 0; h < GPT; ++h) {
        int base = tid + (h << 10);
        #pragma unroll
        for (int j = 0; j < NB; ++j) {           // insert 0 at sorted float4-bits
            const int m = (1 << S.v[j]) - 1;
            base = ((base & ~m) << 1) | (base & m);
        }
        float4 v[VN];
        #pragma unroll
        for (int m = 0; m < VN; ++m) {
            if (!((TM >> m) & 1)) continue;       // untouched: skip load
            v[m] = st4[SWZ4(base | off4(m, NB, ps.b0, ps.b1, ps.b2))];
        }

        apply_g<PI, 0, VN>(v, gcs, L);
        if constexpr (ps.ng > 1) apply_g<PI, 1, VN>(v, gcs, L);
        if constexpr (ps.ng > 2) apply_g<PI, 2, VN>(v, gcs, L);

        #pragma unroll
        for (int m = 0; m < VN; ++m) {
            if (!((TM >> m) & 1)) continue;       // untouched: skip store
            st4[SWZ4(base | off4(m, NB, ps.b0, ps.b1, ps.b2))] = v[m];
        }
        __builtin_amdgcn_sched_barrier(0);
    }
}

template<int PI>
struct RunPasses {
    static __device__ __forceinline__ void go(float4* st4, const float2* gcs, int tid, int L) {
        __syncthreads();
        do_pass<PI>(st4, gcs, tid, L);
        RunPasses<PI + 1>::go(st4, gcs, tid, L);
    }
};
template<> struct RunPasses<18> {
    static __device__ __forceinline__ void go(float4*, const float2*, int, int) {}
};

__global__ __launch_bounds__(THREADS)
void qsim_kernel(const float* __restrict__ params,
                 unsigned int* __restrict__ out_u32) {
    __shared__ float4 st4[NF4];        // 128 KiB; element f = amps (2f, 2f+1), swizzled
    __shared__ float2 gcs[NPARAMS];

    const int b   = blockIdx.x;
    const int tid = threadIdx.x;

    if (tid < NPARAMS) {
        float s, c;
        sincosf(0.5f * params[b * NPARAMS + tid], &s, &c);
        gcs[tid] = make_float2(c, s);
    }
    for (int k = tid; k < NF4; k += THREADS)
        st4[k] = make_float4(k == 0 ? 1.f : 0.f, 0.f, 0.f, 0.f);   // SWZ4(0)=0

    #pragma unroll 1
    for (int layer = 0; layer < 2; ++layer)
        RunPasses<0>::go(st4, gcs, tid, layer * 70);
    __syncthreads();

    // ---- epilogue: float4 f -> words 2f (im|re), 2f+1 (im|re); coalesced uint2 ----
    uint2* ob = (uint2*)(out_u32 + (size_t)b * NSTATE);
    #pragma unroll
    for (int j = 0; j < 8; ++j) {
        const int f = tid + j * 1024;
        const float4 F = st4[SWZ4(f)];
        uint2 w;
        w.x = f2bf(F.y) | (f2bf(F.x) << 16);   // amp 2f   : low=Im, high=Re
        w.y = f2bf(F.w) | (f2bf(F.z) << 16);   // amp 2f+1
        ob[f] = w;
    }
}

extern "C" void kernel_launch(void* const* d_in, const int* in_sizes, int n_in,
                              void* d_out, int out_size, void* d_ws, size_t ws_size,
                              hipStream_t stream) {
    const float* params = (const float*)d_in[0];
    unsigned int* out = (unsigned int*)d_out;
    qsim_kernel<<<BATCH, THREADS, 0, stream>>>(params, out);
}

// Round 32
// 54.471 us; speedup vs baseline: 2.0615x; 1.1073x over previous
//
#include <hip/hip_runtime.h>
#include <math.h>

constexpr int NQ      = 14;
constexpr int NSTATE  = 1 << 14;    // 16384 amps
constexpr int NF4     = NSTATE / 2; // 8192 float4 (amp pair) elements
constexpr int NPARAMS = 140;
constexpr int BATCH   = 128;
constexpr int THREADS = 1024;

__device__ __forceinline__ unsigned int f2bf(float f) {
    union { float f; unsigned int u; } v; v.f = f;
    return (v.u + 0x7FFFu + ((v.u >> 16) & 1u)) >> 16;
}
// float4-index swizzle: XOR bits 3-5 into bits 0-2 (involution).
__device__ __forceinline__ int SWZ4(int f) { return f ^ ((f >> 3) & 7); }

// SU(2) pair update: b0 = u*a0 + v*a1 ; b1 = -conj(v)*a0 + conj(u)*a1
__device__ __forceinline__ void u_half2(float& ax, float& ay, float& bx, float& by,
                                        float ur, float ui, float vr, float vi) {
    float a0x = ax, a0y = ay, a1x = bx, a1y = by;
    ax =  ur*a0x - ui*a0y + vr*a1x - vi*a1y;
    ay =  ur*a0y + ui*a0x + vr*a1y + vi*a1x;
    bx = -vr*a0x - vi*a0y + ur*a1x + ui*a1y;
    by = -vr*a0y + vi*a0x + ur*a1y - ui*a1x;
}
__device__ __forceinline__ void crx_half(float& ax, float& ay, float& bx, float& by,
                                         float cr, float sr) {
    float a0x = ax, a0y = ay, a1x = bx, a1y = by;
    ax = cr*a0x + sr*a1y;  ay = cr*a0y - sr*a1x;
    bx = cr*a1x + sr*a0y;  by = cr*a1y - sr*a0x;
}

// gate: type 0 = fused 1q on state bit t (pb,pb+1,pb+2 = RX,RY,RZ angles);
//       type 1 = CRX control bit c -> target bit t. bit 0 = intra-float4.
// pb is ABSOLUTE param index (layer offsets baked in).
struct G  { int type, pb, c, t; };
struct P2 { int nb, b0, b1, b2, ng; G g[7]; };

// 31 passes, whole circuit. Built from the verified R31 schedule by
// commutation-fusing the asc ring into the 1q passes (disjoint-support
// swaps only; order of overlapping gates preserved — checked gate-by-gate).
constexpr P2 PS[31] = {
    // ---- layer 0 ----
    {3,13,12,11, 5, {{0,0,0,13},{0,3,0,12},{0,6,0,11},{1,42,13,12},{1,43,12,11}}},
    {2,11,10,0,  2, {{0,9,0,10},{1,44,11,10}}},
    {3,10,9,8,   4, {{0,12,0,9},{0,15,0,8},{1,45,10,9},{1,46,9,8}}},
    {2,8,7,0,    2, {{0,18,0,7},{1,47,8,7}}},
    {3,7,6,5,    4, {{0,21,0,6},{0,24,0,5},{1,48,7,6},{1,49,6,5}}},
    {2,5,4,0,    2, {{0,27,0,4},{1,50,5,4}}},
    {3,4,3,2,    4, {{0,30,0,3},{0,33,0,2},{1,51,4,3},{1,52,3,2}}},
    {2,2,1,0,    2, {{0,36,0,1},{1,53,2,1}}},
    {1,1,0,0,    2, {{0,39,0,0},{1,54,1,0}}},
    {3,13,2,1,   3, {{1,55,0,13},{1,56,0,1},{1,57,1,2}}},
    {3,4,3,2,    2, {{1,58,2,3},{1,59,3,4}}},
    {3,6,5,4,    2, {{1,60,4,5},{1,61,5,6}}},
    {3,8,7,6,    2, {{1,62,6,7},{1,63,7,8}}},
    {3,10,9,8,   2, {{1,64,8,9},{1,65,9,10}}},
    {3,12,11,10, 2, {{1,66,10,11},{1,67,11,12}}},
    // ---- layer boundary merge: desc end (L0) + 1q trio + asc head (L1) ----
    {3,13,12,11, 7, {{1,68,12,13},{1,69,13,0},{0,70,0,13},{0,73,0,12},{0,76,0,11},
                     {1,112,13,12},{1,113,12,11}}},
    // ---- layer 1 ----
    {2,11,10,0,  2, {{0,79,0,10},{1,114,11,10}}},
    {3,10,9,8,   4, {{0,82,0,9},{0,85,0,8},{1,115,10,9},{1,116,9,8}}},
    {2,8,7,0,    2, {{0,88,0,7},{1,117,8,7}}},
    {3,7,6,5,    4, {{0,91,0,6},{0,94,0,5},{1,118,7,6},{1,119,6,5}}},
    {2,5,4,0,    2, {{0,97,0,4},{1,120,5,4}}},
    {3,4,3,2,    4, {{0,100,0,3},{0,103,0,2},{1,121,4,3},{1,122,3,2}}},
    {2,2,1,0,    2, {{0,106,0,1},{1,123,2,1}}},
    {1,1,0,0,    2, {{0,109,0,0},{1,124,1,0}}},
    {3,13,2,1,   3, {{1,125,0,13},{1,126,0,1},{1,127,1,2}}},
    {3,4,3,2,    2, {{1,128,2,3},{1,129,3,4}}},
    {3,6,5,4,    2, {{1,130,4,5},{1,131,5,6}}},
    {3,8,7,6,    2, {{1,132,6,7},{1,133,7,8}}},
    {3,10,9,8,   2, {{1,134,8,9},{1,135,9,10}}},
    {3,12,11,10, 2, {{1,136,10,11},{1,137,11,12}}},
    {2,13,12,0,  2, {{1,138,12,13},{1,139,13,0}}},
};

struct Sorted { int v[3]; };
constexpr Sorted sort3(int a, int b, int c) {
    Sorted s{{a, b, c}};
    for (int i = 0; i < 3; ++i)
        for (int j = 0; j < 2; ++j)
            if (s.v[j] > s.v[j+1]) { int t = s.v[j]; s.v[j] = s.v[j+1]; s.v[j+1] = t; }
    return s;
}
constexpr int off4(int m, int nb, int b0, int b1, int b2) {
    const int B[3] = { b0 - 1, b1 - 1, b2 - 1 };
    int off = 0;
    for (int j = 0; j < nb; ++j) off |= ((m >> (nb-1-j)) & 1) << B[j];
    return off;
}
constexpr int locbit(int b, int b0, int b1, int b2, int nb) {
    return (b == b0) ? (1 << (nb-1)) : (b == b1) ? (1 << (nb-2)) : (1 << (nb-3));
}
// which v-elements any gate in the pass reads/writes
constexpr int touch_mask(P2 ps) {
    const int VN = 1 << ps.nb;
    int t = 0;
    for (int gi = 0; gi < ps.ng; ++gi) {
        G g = ps.g[gi];
        if (g.type == 0 || g.c == 0) { t = (1 << VN) - 1; break; }
        int cb = locbit(g.c, ps.b0, ps.b1, ps.b2, ps.nb);
        for (int m = 0; m < VN; ++m) if (m & cb) t |= 1 << m;
    }
    return t;
}

template<int PI, int GI, int VN>
__device__ __forceinline__ void apply_g(float4 (&v)[VN], const float2* gcs) {
    constexpr P2 ps = PS[PI];
    constexpr G  g  = ps.g[GI];
    if constexpr (g.type == 0) {
        const float2 X = gcs[g.pb], Y = gcs[g.pb+1], Z = gcs[g.pb+2];
        const float cx = X.x, sx = X.y, cy = Y.x, sy = Y.y, cz = Z.x, sz = Z.y;
        const float m0r = cy*cx, m0i = sy*sx, m1r = -sy*cx, m1i = -cy*sx;
        const float ur = cz*m0r + sz*m0i, ui = cz*m0i - sz*m0r;
        const float vr = cz*m1r + sz*m1i, vi = cz*m1i - sz*m1r;
        if constexpr (g.t == 0) {
            #pragma unroll
            for (int m = 0; m < VN; ++m)
                u_half2(v[m].x, v[m].y, v[m].z, v[m].w, ur, ui, vr, vi);
        } else {
            constexpr int tb = locbit(g.t, ps.b0, ps.b1, ps.b2, ps.nb);
            #pragma unroll
            for (int m = 0; m < VN; ++m) {
                if (m & tb) continue;
                u_half2(v[m].x, v[m].y, v[m|tb].x, v[m|tb].y, ur, ui, vr, vi);
                u_half2(v[m].z, v[m].w, v[m|tb].z, v[m|tb].w, ur, ui, vr, vi);
            }
        }
    } else {
        const float2 C = gcs[g.pb];
        const float cr = C.x, sr = C.y;
        if constexpr (g.c == 0) {            // control = bit 0: zw halves only
            constexpr int tb = locbit(g.t, ps.b0, ps.b1, ps.b2, ps.nb);
            #pragma unroll
            for (int m = 0; m < VN; ++m) {
                if (m & tb) continue;
                crx_half(v[m].z, v[m].w, v[m|tb].z, v[m|tb].w, cr, sr);
            }
        } else if constexpr (g.t == 0) {     // target = bit 0: intra-float4
            constexpr int cb = locbit(g.c, ps.b0, ps.b1, ps.b2, ps.nb);
            #pragma unroll
            for (int m = 0; m < VN; ++m) {
                if (!(m & cb)) continue;
                crx_half(v[m].x, v[m].y, v[m].z, v[m].w, cr, sr);
            }
        } else {
            constexpr int cb = locbit(g.c, ps.b0, ps.b1, ps.b2, ps.nb);
            constexpr int tb = locbit(g.t, ps.b0, ps.b1, ps.b2, ps.nb);
            #pragma unroll
            for (int m = 0; m < VN; ++m) {
                if (!(m & cb) || (m & tb)) continue;
                crx_half(v[m].x, v[m].y, v[m|tb].x, v[m|tb].y, cr, sr);
                crx_half(v[m].z, v[m].w, v[m|tb].z, v[m|tb].w, cr, sr);
            }
        }
    }
}

template<int PI, int GI, int VN>
__device__ __forceinline__ void apply_chain(float4 (&v)[VN], const float2* gcs) {
    if constexpr (GI < PS[PI].ng) {
        apply_g<PI, GI, VN>(v, gcs);
        apply_chain<PI, GI + 1, VN>(v, gcs);
    }
}

template<int PI>
__device__ __forceinline__ void do_pass(float4* st4, const float2* gcs, int tid) {
    constexpr P2 ps = PS[PI];
    constexpr int NB  = ps.nb;
    constexpr int VN  = 1 << NB;
    constexpr int GPT = 8 >> NB;
    constexpr int TM  = touch_mask(ps);
    constexpr Sorted S = sort3(ps.b0 - 1, (NB > 1 ? ps.b1 - 1 : 99), (NB > 2 ? ps.b2 - 1 : 99));

    #pragma unroll
    for (int h = 0; h < GPT; ++h) {
        int base = tid + (h << 10);
        #pragma unroll
        for (int j = 0; j < NB; ++j) {           // insert 0 at sorted float4-bits
            const int m = (1 << S.v[j]) - 1;
            base = ((base & ~m) << 1) | (base & m);
        }
        float4 v[VN];
        #pragma unroll
        for (int m = 0; m < VN; ++m) {
            if (!((TM >> m) & 1)) continue;       // untouched: skip load
            v[m] = st4[SWZ4(base | off4(m, NB, ps.b0, ps.b1, ps.b2))];
        }

        apply_chain<PI, 0, VN>(v, gcs);

        #pragma unroll
        for (int m = 0; m < VN; ++m) {
            if (!((TM >> m) & 1)) continue;       // untouched: skip store
            st4[SWZ4(base | off4(m, NB, ps.b0, ps.b1, ps.b2))] = v[m];
        }
        __builtin_amdgcn_sched_barrier(0);
    }
}

template<int PI>
struct RunPasses {
    static __device__ __forceinline__ void go(float4* st4, const float2* gcs, int tid) {
        __syncthreads();
        do_pass<PI>(st4, gcs, tid);
        RunPasses<PI + 1>::go(st4, gcs, tid);
    }
};
template<> struct RunPasses<31> {
    static __device__ __forceinline__ void go(float4*, const float2*, int) {}
};

__global__
__attribute__((amdgpu_flat_work_group_size(1024, 1024)))
__attribute__((amdgpu_num_vgpr(128)))   // 4 waves/SIMD occupancy -> 128 regs legal
void qsim_kernel(const float* __restrict__ params,
                 unsigned int* __restrict__ out_u32) {
    __shared__ float4 st4[NF4];        // 128 KiB; element f = amps (2f, 2f+1), swizzled
    __shared__ float2 gcs[NPARAMS];

    const int b   = blockIdx.x;
    const int tid = threadIdx.x;

    if (tid < NPARAMS) {
        float s, c;
        sincosf(0.5f * params[b * NPARAMS + tid], &s, &c);
        gcs[tid] = make_float2(c, s);
    }
    for (int k = tid; k < NF4; k += THREADS)
        st4[k] = make_float4(k == 0 ? 1.f : 0.f, 0.f, 0.f, 0.f);   // SWZ4(0)=0

    RunPasses<0>::go(st4, gcs, tid);
    __syncthreads();

    // ---- epilogue: float4 f -> words 2f (im|re), 2f+1 (im|re); coalesced uint2 ----
    uint2* ob = (uint2*)(out_u32 + (size_t)b * NSTATE);
    #pragma unroll
    for (int j = 0; j < 8; ++j) {
        const int f = tid + j * 1024;
        const float4 F = st4[SWZ4(f)];
        uint2 w;
        w.x = f2bf(F.y) | (f2bf(F.x) << 16);   // amp 2f   : low=Im, high=Re
        w.y = f2bf(F.w) | (f2bf(F.z) << 16);   // amp 2f+1
        ob[f] = w;
    }
}

extern "C" void kernel_launch(void* const* d_in, const int* in_sizes, int n_in,
                              void* d_out, int out_size, void* d_ws, size_t ws_size,
                              hipStream_t stream) {
    const float* params = (const float*)d_in[0];
    unsigned int* out = (unsigned int*)d_out;
    qsim_kernel<<<BATCH, THREADS, 0, stream>>>(params, out);
}